// Round 1
// baseline (11416.260 us; speedup 1.0000x reference)
//
#include <hip/hip_runtime.h>

#define NRAYS 8192
#define NS 128

__device__ __forceinline__ float clampf(float x, float lo, float hi) {
    return fminf(fmaxf(x, lo), hi);
}

__device__ __forceinline__ void plane_interp(const float* __restrict__ g,
                                             float ca, float cb, float o[3]) {
    // grid_sample semantics, align_corners=True, border padding. reso = 128x128.
    float pa = clampf((ca + 1.f) * (0.5f * 127.f), 0.f, 127.f);
    float pb = clampf((cb + 1.f) * (0.5f * 127.f), 0.f, 127.f);
    int la = (int)pa; if (la > 126) la = 126;   // pa >= 0, int cast == floor
    int lb = (int)pb; if (lb > 126) lb = 126;
    float fa = pa - (float)la, fb = pb - (float)lb;
    float w00 = (1.f - fa) * (1.f - fb);
    float w01 = (1.f - fa) * fb;
    float w10 = fa * (1.f - fb);
    float w11 = fa * fb;
    const float* p = g + la * 128 + lb;
#pragma unroll
    for (int c = 0; c < 3; ++c) {
        const float* q = p + c * 16384;
        o[c] = q[0] * w00 + q[1] * w01 + q[128] * w10 + q[129] * w11;
    }
}

__global__ __launch_bounds__(128)
void nerf_fused(const float* __restrict__ rays_o,
                const float* __restrict__ rays_d,
                const float* __restrict__ bg_color,
                const float* __restrict__ plane01,
                const float* __restrict__ plane02,
                const float* __restrict__ plane12,
                const float* __restrict__ features,
                const float* __restrict__ w1, const float* __restrict__ b1,
                const float* __restrict__ w2, const float* __restrict__ b2,
                const float* __restrict__ wc1, const float* __restrict__ bc1,
                const float* __restrict__ wc2, const float* __restrict__ bc2,
                const float* __restrict__ aabb,
                float* __restrict__ out)
{
    __shared__ float s_w1[32 * 64];
    __shared__ float s_w2[64 * 16];
    __shared__ float s_wc1[18 * 64];
    __shared__ float s_wc2[64 * 3];
    __shared__ float s_b1[64];
    __shared__ float s_b2[16];
    __shared__ float s_bc1[64];
    __shared__ float s_bc2[3];
    __shared__ float s_wavesum[2];
    __shared__ float s_red[2][4];

    const int tid = threadIdx.x;

    // --- stage weights to LDS (wave-uniform broadcast reads later) ---
    for (int i = tid; i < 32 * 64; i += 128) s_w1[i] = w1[i];
    for (int i = tid; i < 64 * 16; i += 128) s_w2[i] = w2[i];
    for (int i = tid; i < 18 * 64; i += 128) s_wc1[i] = wc1[i];
    for (int i = tid; i < 64 * 3;  i += 128) s_wc2[i] = wc2[i];
    if (tid < 64) s_b1[tid] = b1[tid];
    if (tid < 16) s_b2[tid] = b2[tid];
    if (tid < 64) s_bc1[tid] = bc1[tid];
    if (tid < 3)  s_bc2[tid] = bc2[tid];
    __syncthreads();

    const int ray = blockIdx.x;

    // --- per-ray setup (redundant across the 128 threads; cheap) ---
    float ox = rays_o[ray * 3 + 0], oy = rays_o[ray * 3 + 1], oz = rays_o[ray * 3 + 2];
    float dx = rays_d[ray * 3 + 0], dy = rays_d[ray * 3 + 1], dz = rays_d[ray * 3 + 2];
    float rn = rsqrtf(dx * dx + dy * dy + dz * dz);
    dx *= rn; dy *= rn; dz *= rn;

    float lo0 = aabb[0], lo1 = aabb[1], lo2 = aabb[2];
    float hi0 = aabb[3], hi1 = aabb[4], hi2 = aabb[5];

    float invx = 1.f / dx, invy = 1.f / dy, invz = 1.f / dz;
    float tx0 = (lo0 - ox) * invx, tx1 = (hi0 - ox) * invx;
    float ty0 = (lo1 - oy) * invy, ty1 = (hi1 - oy) * invy;
    float tz0 = (lo2 - oz) * invz, tz1 = (hi2 - oz) * invz;
    float tnear = fmaxf(fmaxf(fminf(tx0, tx1), fminf(ty0, ty1)), fminf(tz0, tz1));
    tnear = fmaxf(tnear, 0.f);
    float tfar = fminf(fminf(fmaxf(tx0, tx1), fmaxf(ty0, ty1)), fmaxf(tz0, tz1));
    tfar = fmaxf(tfar, tnear);
    float delta = (tfar - tnear) * (1.f / (float)NS);

    // --- this thread's sample point ---
    float t = tnear + delta * ((float)tid + 0.5f);
    float px = ox + dx * t, py = oy + dy * t, pz = oz + dz * t;
    // normalize_coord AABB -> [-1,1]
    px = (px - lo0) * (2.f / (hi0 - lo0)) - 1.f;
    py = (py - lo1) * (2.f / (hi1 - lo1)) - 1.f;
    pz = (pz - lo2) * (2.f / (hi2 - lo2)) - 1.f;

    // --- factorized plane features ---
    float p01[3], p02[3], p12[3];
    plane_interp(plane01, px, py, p01);
    plane_interp(plane02, px, pz, p02);
    plane_interp(plane12, py, pz, p12);
    float gx = p01[0] * p02[0] * p12[0];
    float gy = p01[1] * p02[1] * p12[1];
    float gz = p01[2] * p02[2] * p12[2];

    // --- trilinear feature interp fused into MLP layer 1 ---
    float qx = clampf((gx + 1.f) * (0.5f * 63.f), 0.f, 63.f);
    float qy = clampf((gy + 1.f) * (0.5f * 63.f), 0.f, 63.f);
    float qz = clampf((gz + 1.f) * (0.5f * 63.f), 0.f, 63.f);
    int ixg = (int)qx; if (ixg > 62) ixg = 62;
    int iyg = (int)qy; if (iyg > 62) iyg = 62;
    int izg = (int)qz; if (izg > 62) izg = 62;
    float fx = qx - (float)ixg, fy = qy - (float)iyg, fz = qz - (float)izg;
    float wx0 = 1.f - fx, wy0 = 1.f - fy, wz0 = 1.f - fz;
    float cw0 = wx0 * wy0 * wz0, cw1 = wx0 * wy0 * fz;
    float cw2 = wx0 * fy  * wz0, cw3 = wx0 * fy  * fz;
    float cw4 = fx  * wy0 * wz0, cw5 = fx  * wy0 * fz;
    float cw6 = fx  * fy  * wz0, cw7 = fx  * fy  * fz;
    const float* fbase = features + (ixg * 4096 + iyg * 64 + izg);

    float h[64];
#pragma unroll
    for (int j = 0; j < 64; ++j) h[j] = s_b1[j];
#pragma unroll
    for (int ch = 0; ch < 32; ++ch) {
        const float* f = fbase + ch * 262144;
        float v = cw0 * f[0]    + cw1 * f[1]
                + cw2 * f[64]   + cw3 * f[65]
                + cw4 * f[4096] + cw5 * f[4097]
                + cw6 * f[4160] + cw7 * f[4161];
#pragma unroll
        for (int j = 0; j < 64; ++j) h[j] = fmaf(v, s_w1[ch * 64 + j], h[j]);
    }

    // --- MLP layer 2: relu(h) @ w2 + b2 -> sig_out[16] ---
    float so[16];
#pragma unroll
    for (int o = 0; o < 16; ++o) so[o] = s_b2[o];
#pragma unroll
    for (int j = 0; j < 64; ++j) {
        float hv = fmaxf(h[j], 0.f);
#pragma unroll
        for (int o = 0; o < 16; ++o) so[o] = fmaf(hv, s_w2[j * 16 + o], so[o]);
    }
    float density = __expf(clampf(so[0], -15.f, 15.f));

    // --- color MLP: cin = [d, sig_out[1:]] (18) -> 64 -> relu -> 3 -> sigmoid ---
    float cin[18];
    cin[0] = dx; cin[1] = dy; cin[2] = dz;
#pragma unroll
    for (int k = 0; k < 15; ++k) cin[3 + k] = so[1 + k];

#pragma unroll
    for (int j = 0; j < 64; ++j) h[j] = s_bc1[j];   // reuse h as hc
#pragma unroll
    for (int k = 0; k < 18; ++k) {
        float v = cin[k];
#pragma unroll
        for (int j = 0; j < 64; ++j) h[j] = fmaf(v, s_wc1[k * 64 + j], h[j]);
    }
    float r0 = s_bc2[0], r1 = s_bc2[1], r2 = s_bc2[2];
#pragma unroll
    for (int j = 0; j < 64; ++j) {
        float v = fmaxf(h[j], 0.f);
        r0 = fmaf(v, s_wc2[j * 3 + 0], r0);
        r1 = fmaf(v, s_wc2[j * 3 + 1], r1);
        r2 = fmaf(v, s_wc2[j * 3 + 2], r2);
    }
    r0 = 1.f / (1.f + __expf(-r0));
    r1 = 1.f / (1.f + __expf(-r1));
    r2 = 1.f / (1.f + __expf(-r2));

    // --- per-ray exponential integration ---
    float tau = density * delta;
    float x = tau;
    int lane = tid & 63;
#pragma unroll
    for (int off = 1; off < 64; off <<= 1) {
        float y = __shfl_up(x, off);
        if (lane >= off) x += y;
    }
    if (lane == 63) s_wavesum[tid >> 6] = x;
    __syncthreads();
    if (tid >= 64) x += s_wavesum[0];
    // exclusive transmittance: T = exp(-(incl - tau))
    float T = __expf(tau - x);
    float w = T * (1.f - __expf(-tau));

    float v0 = w * r0, v1 = w * r1, v2 = w * r2, v3 = w;
#pragma unroll
    for (int off = 32; off; off >>= 1) {
        v0 += __shfl_xor(v0, off);
        v1 += __shfl_xor(v1, off);
        v2 += __shfl_xor(v2, off);
        v3 += __shfl_xor(v3, off);
    }
    if (lane == 0) {
        int wv = tid >> 6;
        s_red[wv][0] = v0; s_red[wv][1] = v1; s_red[wv][2] = v2; s_red[wv][3] = v3;
    }
    __syncthreads();
    if (tid == 0) {
        float bg = bg_color[0];
        float c0 = s_red[0][0] + s_red[1][0];
        float c1 = s_red[0][1] + s_red[1][1];
        float c2 = s_red[0][2] + s_red[1][2];
        float a  = s_red[0][3] + s_red[1][3];
        out[ray * 3 + 0] = c0 + (1.f - a) * bg;
        out[ray * 3 + 1] = c1 + (1.f - a) * bg;
        out[ray * 3 + 2] = c2 + (1.f - a) * bg;
    }
}

extern "C" void kernel_launch(void* const* d_in, const int* in_sizes, int n_in,
                              void* d_out, int out_size, void* d_ws, size_t ws_size,
                              hipStream_t stream) {
    const float* rays_o  = (const float*)d_in[0];
    const float* rays_d  = (const float*)d_in[1];
    const float* bg      = (const float*)d_in[2];
    const float* p01     = (const float*)d_in[3];
    const float* p02     = (const float*)d_in[4];
    const float* p12     = (const float*)d_in[5];
    const float* feats   = (const float*)d_in[6];
    const float* w1      = (const float*)d_in[7];
    const float* b1      = (const float*)d_in[8];
    const float* w2      = (const float*)d_in[9];
    const float* b2      = (const float*)d_in[10];
    const float* wc1     = (const float*)d_in[11];
    const float* bc1     = (const float*)d_in[12];
    const float* wc2     = (const float*)d_in[13];
    const float* bc2     = (const float*)d_in[14];
    const float* aabb    = (const float*)d_in[15];
    float* out = (float*)d_out;

    nerf_fused<<<NRAYS, 128, 0, stream>>>(rays_o, rays_d, bg, p01, p02, p12, feats,
                                          w1, b1, w2, b2, wc1, bc1, wc2, bc2, aabb, out);
}

// Round 2
// 6075.832 us; speedup vs baseline: 1.8790x; 1.8790x over previous
//
#include <hip/hip_runtime.h>

#define NRAYS 8192
#define NS 128

__device__ __forceinline__ float clampf(float x, float lo, float hi) {
    return fminf(fmaxf(x, lo), hi);
}

__device__ __forceinline__ void plane_interp(const float* __restrict__ g,
                                             float ca, float cb, float o[3]) {
    // grid_sample semantics, align_corners=True, border padding. reso = 128x128.
    float pa = clampf((ca + 1.f) * (0.5f * 127.f), 0.f, 127.f);
    float pb = clampf((cb + 1.f) * (0.5f * 127.f), 0.f, 127.f);
    int la = (int)pa; if (la > 126) la = 126;
    int lb = (int)pb; if (lb > 126) lb = 126;
    float fa = pa - (float)la, fb = pb - (float)lb;
    float w00 = (1.f - fa) * (1.f - fb);
    float w01 = (1.f - fa) * fb;
    float w10 = fa * (1.f - fb);
    float w11 = fa * fb;
    const float* p = g + la * 128 + lb;
#pragma unroll
    for (int c = 0; c < 3; ++c) {
        const float* q = p + c * 16384;
        o[c] = q[0] * w00 + q[1] * w01 + q[128] * w10 + q[129] * w11;
    }
}

__global__ __launch_bounds__(128)
void nerf_fused(const float* __restrict__ rays_o,
                const float* __restrict__ rays_d,
                const float* __restrict__ bg_color,
                const float* __restrict__ plane01,
                const float* __restrict__ plane02,
                const float* __restrict__ plane12,
                const float* __restrict__ features,
                const float* __restrict__ w1, const float* __restrict__ b1,
                const float* __restrict__ w2, const float* __restrict__ b2,
                const float* __restrict__ wc1, const float* __restrict__ bc1,
                const float* __restrict__ wc2, const float* __restrict__ bc2,
                const float* __restrict__ aabb,
                float* __restrict__ out)
{
    // 16B-aligned so float4 reinterpret reads are legal ds_read_b128
    __shared__ __align__(16) float s_w1[32 * 64];
    __shared__ __align__(16) float s_w2[64 * 16];
    __shared__ __align__(16) float s_wc1[18 * 64];
    __shared__ __align__(16) float s_wc2t[3 * 64];   // transposed: [o][j]
    __shared__ __align__(16) float s_b1[64];
    __shared__ __align__(16) float s_b2[16];
    __shared__ __align__(16) float s_bc1[64];
    __shared__ float s_bc2[3];
    __shared__ float s_wavesum[2];
    __shared__ float s_red[2][4];

    const int tid = threadIdx.x;

    // --- stage weights to LDS ---
    for (int i = tid; i < 32 * 64; i += 128) s_w1[i] = w1[i];
    for (int i = tid; i < 64 * 16; i += 128) s_w2[i] = w2[i];
    for (int i = tid; i < 18 * 64; i += 128) s_wc1[i] = wc1[i];
    for (int i = tid; i < 3 * 64;  i += 128) {
        int o = i >> 6, j = i & 63;
        s_wc2t[i] = wc2[j * 3 + o];
    }
    if (tid < 64) s_b1[tid] = b1[tid];
    if (tid < 16) s_b2[tid] = b2[tid];
    if (tid < 64) s_bc1[tid] = bc1[tid];
    if (tid < 3)  s_bc2[tid] = bc2[tid];
    __syncthreads();

    const int ray = blockIdx.x;

    // --- per-ray setup ---
    float ox = rays_o[ray * 3 + 0], oy = rays_o[ray * 3 + 1], oz = rays_o[ray * 3 + 2];
    float dx = rays_d[ray * 3 + 0], dy = rays_d[ray * 3 + 1], dz = rays_d[ray * 3 + 2];
    float rn = rsqrtf(dx * dx + dy * dy + dz * dz);
    dx *= rn; dy *= rn; dz *= rn;

    float lo0 = aabb[0], lo1 = aabb[1], lo2 = aabb[2];
    float hi0 = aabb[3], hi1 = aabb[4], hi2 = aabb[5];

    float invx = 1.f / dx, invy = 1.f / dy, invz = 1.f / dz;
    float tx0 = (lo0 - ox) * invx, tx1 = (hi0 - ox) * invx;
    float ty0 = (lo1 - oy) * invy, ty1 = (hi1 - oy) * invy;
    float tz0 = (lo2 - oz) * invz, tz1 = (hi2 - oz) * invz;
    float tnear = fmaxf(fmaxf(fminf(tx0, tx1), fminf(ty0, ty1)), fminf(tz0, tz1));
    tnear = fmaxf(tnear, 0.f);
    float tfar = fminf(fminf(fmaxf(tx0, tx1), fmaxf(ty0, ty1)), fmaxf(tz0, tz1));
    tfar = fmaxf(tfar, tnear);
    float delta = (tfar - tnear) * (1.f / (float)NS);

    // --- this thread's sample point ---
    float t = tnear + delta * ((float)tid + 0.5f);
    float px = ox + dx * t, py = oy + dy * t, pz = oz + dz * t;
    px = (px - lo0) * (2.f / (hi0 - lo0)) - 1.f;
    py = (py - lo1) * (2.f / (hi1 - lo1)) - 1.f;
    pz = (pz - lo2) * (2.f / (hi2 - lo2)) - 1.f;

    // --- factorized plane features ---
    float p01[3], p02[3], p12[3];
    plane_interp(plane01, px, py, p01);
    plane_interp(plane02, px, pz, p02);
    plane_interp(plane12, py, pz, p12);
    float gx = p01[0] * p02[0] * p12[0];
    float gy = p01[1] * p02[1] * p12[1];
    float gz = p01[2] * p02[2] * p12[2];

    // --- trilinear setup ---
    float qx = clampf((gx + 1.f) * (0.5f * 63.f), 0.f, 63.f);
    float qy = clampf((gy + 1.f) * (0.5f * 63.f), 0.f, 63.f);
    float qz = clampf((gz + 1.f) * (0.5f * 63.f), 0.f, 63.f);
    int ixg = (int)qx; if (ixg > 62) ixg = 62;
    int iyg = (int)qy; if (iyg > 62) iyg = 62;
    int izg = (int)qz; if (izg > 62) izg = 62;
    float fx = qx - (float)ixg, fy = qy - (float)iyg, fz = qz - (float)izg;
    float wx0 = 1.f - fx, wy0 = 1.f - fy, wz0 = 1.f - fz;
    float cw0 = wx0 * wy0 * wz0, cw1 = wx0 * wy0 * fz;
    float cw2 = wx0 * fy  * wz0, cw3 = wx0 * fy  * fz;
    float cw4 = fx  * wy0 * wz0, cw5 = fx  * wy0 * fz;
    float cw6 = fx  * fy  * wz0, cw7 = fx  * fy  * fz;
    const float* fbase = features + (ixg * 4096 + iyg * 64 + izg);

    // --- layer 1: h = feats @ w1 + b1, gather fused, ch loop ROLLED (no spill) ---
    float h[64];
    {
        const float4* bv = (const float4*)s_b1;
#pragma unroll
        for (int q = 0; q < 16; ++q) {
            float4 b = bv[q];
            h[4 * q + 0] = b.x; h[4 * q + 1] = b.y; h[4 * q + 2] = b.z; h[4 * q + 3] = b.w;
        }
    }
#pragma unroll 2
    for (int ch = 0; ch < 32; ++ch) {
        const float* f = fbase + ch * 262144;
        float v = cw0 * f[0]    + cw1 * f[1]
                + cw2 * f[64]   + cw3 * f[65]
                + cw4 * f[4096] + cw5 * f[4097]
                + cw6 * f[4160] + cw7 * f[4161];
        const float4* wrow = (const float4*)(s_w1 + ch * 64);
#pragma unroll
        for (int q = 0; q < 16; ++q) {
            float4 w = wrow[q];
            h[4 * q + 0] = fmaf(v, w.x, h[4 * q + 0]);
            h[4 * q + 1] = fmaf(v, w.y, h[4 * q + 1]);
            h[4 * q + 2] = fmaf(v, w.z, h[4 * q + 2]);
            h[4 * q + 3] = fmaf(v, w.w, h[4 * q + 3]);
        }
    }

    // --- layer 2: so = relu(h) @ w2 + b2 ---
    float so[16];
    {
        const float4* bv = (const float4*)s_b2;
#pragma unroll
        for (int q = 0; q < 4; ++q) {
            float4 b = bv[q];
            so[4 * q + 0] = b.x; so[4 * q + 1] = b.y; so[4 * q + 2] = b.z; so[4 * q + 3] = b.w;
        }
    }
#pragma unroll
    for (int j = 0; j < 64; ++j) {
        float hv = fmaxf(h[j], 0.f);
        const float4* wrow = (const float4*)(s_w2 + j * 16);
#pragma unroll
        for (int q = 0; q < 4; ++q) {
            float4 w = wrow[q];
            so[4 * q + 0] = fmaf(hv, w.x, so[4 * q + 0]);
            so[4 * q + 1] = fmaf(hv, w.y, so[4 * q + 1]);
            so[4 * q + 2] = fmaf(hv, w.z, so[4 * q + 2]);
            so[4 * q + 3] = fmaf(hv, w.w, so[4 * q + 3]);
        }
    }
    float density = __expf(clampf(so[0], -15.f, 15.f));

    // --- color MLP layer 1: hc = cin @ wc1 + bc1 ; cin = [d, so[1:16]] ---
    {
        const float4* bv = (const float4*)s_bc1;
#pragma unroll
        for (int q = 0; q < 16; ++q) {
            float4 b = bv[q];
            h[4 * q + 0] = b.x; h[4 * q + 1] = b.y; h[4 * q + 2] = b.z; h[4 * q + 3] = b.w;
        }
    }
#pragma unroll
    for (int k = 0; k < 18; ++k) {
        float v = (k == 0) ? dx : (k == 1) ? dy : (k == 2) ? dz : so[k - 2];
        const float4* wrow = (const float4*)(s_wc1 + k * 64);
#pragma unroll
        for (int q = 0; q < 16; ++q) {
            float4 w = wrow[q];
            h[4 * q + 0] = fmaf(v, w.x, h[4 * q + 0]);
            h[4 * q + 1] = fmaf(v, w.y, h[4 * q + 1]);
            h[4 * q + 2] = fmaf(v, w.z, h[4 * q + 2]);
            h[4 * q + 3] = fmaf(v, w.w, h[4 * q + 3]);
        }
    }
    // relu in place, then color layer 2 from transposed weights
#pragma unroll
    for (int j = 0; j < 64; ++j) h[j] = fmaxf(h[j], 0.f);

    float rgb[3];
#pragma unroll
    for (int o = 0; o < 3; ++o) {
        float acc = s_bc2[o];
        const float4* wrow = (const float4*)(s_wc2t + o * 64);
#pragma unroll
        for (int q = 0; q < 16; ++q) {
            float4 w = wrow[q];
            acc = fmaf(h[4 * q + 0], w.x, acc);
            acc = fmaf(h[4 * q + 1], w.y, acc);
            acc = fmaf(h[4 * q + 2], w.z, acc);
            acc = fmaf(h[4 * q + 3], w.w, acc);
        }
        rgb[o] = 1.f / (1.f + __expf(-acc));
    }

    // --- per-ray exponential integration ---
    float tau = density * delta;
    float x = tau;
    int lane = tid & 63;
#pragma unroll
    for (int off = 1; off < 64; off <<= 1) {
        float y = __shfl_up(x, off);
        if (lane >= off) x += y;
    }
    if (lane == 63) s_wavesum[tid >> 6] = x;
    __syncthreads();
    if (tid >= 64) x += s_wavesum[0];
    float T = __expf(tau - x);
    float w = T * (1.f - __expf(-tau));

    float v0 = w * rgb[0], v1 = w * rgb[1], v2 = w * rgb[2], v3 = w;
#pragma unroll
    for (int off = 32; off; off >>= 1) {
        v0 += __shfl_xor(v0, off);
        v1 += __shfl_xor(v1, off);
        v2 += __shfl_xor(v2, off);
        v3 += __shfl_xor(v3, off);
    }
    if (lane == 0) {
        int wv = tid >> 6;
        s_red[wv][0] = v0; s_red[wv][1] = v1; s_red[wv][2] = v2; s_red[wv][3] = v3;
    }
    __syncthreads();
    if (tid == 0) {
        float bg = bg_color[0];
        float c0 = s_red[0][0] + s_red[1][0];
        float c1 = s_red[0][1] + s_red[1][1];
        float c2 = s_red[0][2] + s_red[1][2];
        float a  = s_red[0][3] + s_red[1][3];
        out[ray * 3 + 0] = c0 + (1.f - a) * bg;
        out[ray * 3 + 1] = c1 + (1.f - a) * bg;
        out[ray * 3 + 2] = c2 + (1.f - a) * bg;
    }
}

extern "C" void kernel_launch(void* const* d_in, const int* in_sizes, int n_in,
                              void* d_out, int out_size, void* d_ws, size_t ws_size,
                              hipStream_t stream) {
    const float* rays_o  = (const float*)d_in[0];
    const float* rays_d  = (const float*)d_in[1];
    const float* bg      = (const float*)d_in[2];
    const float* p01     = (const float*)d_in[3];
    const float* p02     = (const float*)d_in[4];
    const float* p12     = (const float*)d_in[5];
    const float* feats   = (const float*)d_in[6];
    const float* w1      = (const float*)d_in[7];
    const float* b1      = (const float*)d_in[8];
    const float* w2      = (const float*)d_in[9];
    const float* b2      = (const float*)d_in[10];
    const float* wc1     = (const float*)d_in[11];
    const float* bc1     = (const float*)d_in[12];
    const float* wc2     = (const float*)d_in[13];
    const float* bc2     = (const float*)d_in[14];
    const float* aabb    = (const float*)d_in[15];
    float* out = (float*)d_out;

    nerf_fused<<<NRAYS, 128, 0, stream>>>(rays_o, rays_d, bg, p01, p02, p12, feats,
                                          w1, b1, w2, b2, wc1, bc1, wc2, bc2, aabb, out);
}

// Round 3
// 2220.528 us; speedup vs baseline: 5.1412x; 2.7362x over previous
//
#include <hip/hip_runtime.h>

#define NRAYS 8192
#define NS 128

typedef float v16f __attribute__((ext_vector_type(16)));

__device__ __forceinline__ float clampf(float x, float lo, float hi) {
    return fminf(fmaxf(x, lo), hi);
}

__device__ __forceinline__ v16f relu16(v16f x) {
#pragma unroll
    for (int i = 0; i < 16; ++i) x[i] = fmaxf(x[i], 0.f);
    return x;
}

__device__ __forceinline__ void plane_interp(const float* __restrict__ g,
                                             float ca, float cb, float o[3]) {
    // grid_sample semantics, align_corners=True, border padding. reso = 128x128.
    float pa = clampf((ca + 1.f) * (0.5f * 127.f), 0.f, 127.f);
    float pb = clampf((cb + 1.f) * (0.5f * 127.f), 0.f, 127.f);
    int la = (int)pa; if (la > 126) la = 126;
    int lb = (int)pb; if (lb > 126) lb = 126;
    float fa = pa - (float)la, fb = pb - (float)lb;
    float w00 = (1.f - fa) * (1.f - fb);
    float w01 = (1.f - fa) * fb;
    float w10 = fa * (1.f - fb);
    float w11 = fa * fb;
    const float* p = g + la * 128 + lb;
#pragma unroll
    for (int c = 0; c < 3; ++c) {
        const float* q = p + c * 16384;
        o[c] = q[0] * w00 + q[1] * w01 + q[128] * w10 + q[129] * w11;
    }
}

__global__ __launch_bounds__(128)
void nerf_fused(const float* __restrict__ rays_o,
                const float* __restrict__ rays_d,
                const float* __restrict__ bg_color,
                const float* __restrict__ plane01,
                const float* __restrict__ plane02,
                const float* __restrict__ plane12,
                const float* __restrict__ features,
                const float* __restrict__ w1, const float* __restrict__ b1,
                const float* __restrict__ w2, const float* __restrict__ b2,
                const float* __restrict__ wc1, const float* __restrict__ bc1,
                const float* __restrict__ wc2, const float* __restrict__ bc2,
                const float* __restrict__ aabb,
                float* __restrict__ out)
{
    // 64B-aligned so v16f reinterpret reads are legal (emit 4x ds_read_b128)
    __shared__ __align__(64) float s_w1[32 * 64];
    __shared__ __align__(64) float s_w2[64 * 16];
    __shared__ __align__(64) float s_wc1[18 * 64];
    __shared__ __align__(64) float s_wc2t[3 * 64];   // transposed: [o][j]
    __shared__ __align__(64) float s_b1[64];
    __shared__ __align__(64) float s_b2[16];
    __shared__ __align__(64) float s_bc1[64];
    __shared__ float s_bc2[3];
    __shared__ float s_wavesum[2];
    __shared__ float s_red[2][4];

    const int tid = threadIdx.x;

    // --- stage weights to LDS ---
    for (int i = tid; i < 32 * 64; i += 128) s_w1[i] = w1[i];
    for (int i = tid; i < 64 * 16; i += 128) s_w2[i] = w2[i];
    for (int i = tid; i < 18 * 64; i += 128) s_wc1[i] = wc1[i];
    for (int i = tid; i < 3 * 64;  i += 128) {
        int o = i >> 6, j = i & 63;
        s_wc2t[i] = wc2[j * 3 + o];
    }
    if (tid < 64) s_b1[tid] = b1[tid];
    if (tid < 16) s_b2[tid] = b2[tid];
    if (tid < 64) s_bc1[tid] = bc1[tid];
    if (tid < 3)  s_bc2[tid] = bc2[tid];
    __syncthreads();

    const int ray = blockIdx.x;

    // --- per-ray setup ---
    float ox = rays_o[ray * 3 + 0], oy = rays_o[ray * 3 + 1], oz = rays_o[ray * 3 + 2];
    float dx = rays_d[ray * 3 + 0], dy = rays_d[ray * 3 + 1], dz = rays_d[ray * 3 + 2];
    float rn = rsqrtf(dx * dx + dy * dy + dz * dz);
    dx *= rn; dy *= rn; dz *= rn;

    float lo0 = aabb[0], lo1 = aabb[1], lo2 = aabb[2];
    float hi0 = aabb[3], hi1 = aabb[4], hi2 = aabb[5];

    float invx = 1.f / dx, invy = 1.f / dy, invz = 1.f / dz;
    float tx0 = (lo0 - ox) * invx, tx1 = (hi0 - ox) * invx;
    float ty0 = (lo1 - oy) * invy, ty1 = (hi1 - oy) * invy;
    float tz0 = (lo2 - oz) * invz, tz1 = (hi2 - oz) * invz;
    float tnear = fmaxf(fmaxf(fminf(tx0, tx1), fminf(ty0, ty1)), fminf(tz0, tz1));
    tnear = fmaxf(tnear, 0.f);
    float tfar = fminf(fminf(fmaxf(tx0, tx1), fmaxf(ty0, ty1)), fmaxf(tz0, tz1));
    tfar = fmaxf(tfar, tnear);
    float delta = (tfar - tnear) * (1.f / (float)NS);

    // --- this thread's sample point ---
    float t = tnear + delta * ((float)tid + 0.5f);
    float px = ox + dx * t, py = oy + dy * t, pz = oz + dz * t;
    px = (px - lo0) * (2.f / (hi0 - lo0)) - 1.f;
    py = (py - lo1) * (2.f / (hi1 - lo1)) - 1.f;
    pz = (pz - lo2) * (2.f / (hi2 - lo2)) - 1.f;

    // --- factorized plane features ---
    float p01[3], p02[3], p12[3];
    plane_interp(plane01, px, py, p01);
    plane_interp(plane02, px, pz, p02);
    plane_interp(plane12, py, pz, p12);
    float gx = p01[0] * p02[0] * p12[0];
    float gy = p01[1] * p02[1] * p12[1];
    float gz = p01[2] * p02[2] * p12[2];

    // --- trilinear setup ---
    float qx = clampf((gx + 1.f) * (0.5f * 63.f), 0.f, 63.f);
    float qy = clampf((gy + 1.f) * (0.5f * 63.f), 0.f, 63.f);
    float qz = clampf((gz + 1.f) * (0.5f * 63.f), 0.f, 63.f);
    int ixg = (int)qx; if (ixg > 62) ixg = 62;
    int iyg = (int)qy; if (iyg > 62) iyg = 62;
    int izg = (int)qz; if (izg > 62) izg = 62;
    float fx = qx - (float)ixg, fy = qy - (float)iyg, fz = qz - (float)izg;
    float wx0 = 1.f - fx, wy0 = 1.f - fy, wz0 = 1.f - fz;
    float cw0 = wx0 * wy0 * wz0, cw1 = wx0 * wy0 * fz;
    float cw2 = wx0 * fy  * wz0, cw3 = wx0 * fy  * fz;
    float cw4 = fx  * wy0 * wz0, cw5 = fx  * wy0 * fz;
    float cw6 = fx  * fy  * wz0, cw7 = fx  * fy  * fz;
    const float* fbase = features + (ixg * 4096 + iyg * 64 + izg);

    // --- layer 1: h = feats @ w1 + b1 (h lives in SSA vectors -> registers) ---
    v16f h0 = ((const v16f*)s_b1)[0];
    v16f h1 = ((const v16f*)s_b1)[1];
    v16f h2 = ((const v16f*)s_b1)[2];
    v16f h3 = ((const v16f*)s_b1)[3];
#pragma unroll 2
    for (int ch = 0; ch < 32; ++ch) {
        const float* f = fbase + ch * 262144;
        float v = cw0 * f[0]    + cw1 * f[1]
                + cw2 * f[64]   + cw3 * f[65]
                + cw4 * f[4096] + cw5 * f[4097]
                + cw6 * f[4160] + cw7 * f[4161];
        const v16f* wr = (const v16f*)(s_w1 + ch * 64);
        h0 += v * wr[0];
        h1 += v * wr[1];
        h2 += v * wr[2];
        h3 += v * wr[3];
    }

    // --- layer 2: so = relu(h) @ w2 + b2 ---
    v16f so = ((const v16f*)s_b2)[0];
    h0 = relu16(h0); h1 = relu16(h1); h2 = relu16(h2); h3 = relu16(h3);
#pragma unroll
    for (int j = 0; j < 64; ++j) {
        float hv;
        if (j < 16)      hv = h0[j];
        else if (j < 32) hv = h1[j - 16];
        else if (j < 48) hv = h2[j - 32];
        else             hv = h3[j - 48];
        const v16f* wr = (const v16f*)(s_w2 + j * 16);
        so += hv * wr[0];
    }
    float density = __expf(clampf(so[0], -15.f, 15.f));

    // --- color MLP layer 1: hc = cin @ wc1 + bc1 ; cin = [d, so[1:16]] ---
    h0 = ((const v16f*)s_bc1)[0];
    h1 = ((const v16f*)s_bc1)[1];
    h2 = ((const v16f*)s_bc1)[2];
    h3 = ((const v16f*)s_bc1)[3];
#pragma unroll
    for (int k = 0; k < 18; ++k) {
        float v = (k == 0) ? dx : (k == 1) ? dy : (k == 2) ? dz : so[k - 2];
        const v16f* wr = (const v16f*)(s_wc1 + k * 64);
        h0 += v * wr[0];
        h1 += v * wr[1];
        h2 += v * wr[2];
        h3 += v * wr[3];
    }
    h0 = relu16(h0); h1 = relu16(h1); h2 = relu16(h2); h3 = relu16(h3);

    float rgb[3];
#pragma unroll
    for (int o = 0; o < 3; ++o) {
        const v16f* wr = (const v16f*)(s_wc2t + o * 64);
        v16f p = h0 * wr[0] + h1 * wr[1] + h2 * wr[2] + h3 * wr[3];
        float acc = s_bc2[o];
#pragma unroll
        for (int i = 0; i < 16; ++i) acc += p[i];
        rgb[o] = 1.f / (1.f + __expf(-acc));
    }

    // --- per-ray exponential integration ---
    float tau = density * delta;
    float x = tau;
    int lane = tid & 63;
#pragma unroll
    for (int off = 1; off < 64; off <<= 1) {
        float y = __shfl_up(x, off);
        if (lane >= off) x += y;
    }
    if (lane == 63) s_wavesum[tid >> 6] = x;
    __syncthreads();
    if (tid >= 64) x += s_wavesum[0];
    float T = __expf(tau - x);
    float w = T * (1.f - __expf(-tau));

    float v0 = w * rgb[0], v1 = w * rgb[1], v2 = w * rgb[2], v3 = w;
#pragma unroll
    for (int off = 32; off; off >>= 1) {
        v0 += __shfl_xor(v0, off);
        v1 += __shfl_xor(v1, off);
        v2 += __shfl_xor(v2, off);
        v3 += __shfl_xor(v3, off);
    }
    if (lane == 0) {
        int wv = tid >> 6;
        s_red[wv][0] = v0; s_red[wv][1] = v1; s_red[wv][2] = v2; s_red[wv][3] = v3;
    }
    __syncthreads();
    if (tid == 0) {
        float bg = bg_color[0];
        float c0 = s_red[0][0] + s_red[1][0];
        float c1 = s_red[0][1] + s_red[1][1];
        float c2 = s_red[0][2] + s_red[1][2];
        float a  = s_red[0][3] + s_red[1][3];
        out[ray * 3 + 0] = c0 + (1.f - a) * bg;
        out[ray * 3 + 1] = c1 + (1.f - a) * bg;
        out[ray * 3 + 2] = c2 + (1.f - a) * bg;
    }
}

extern "C" void kernel_launch(void* const* d_in, const int* in_sizes, int n_in,
                              void* d_out, int out_size, void* d_ws, size_t ws_size,
                              hipStream_t stream) {
    const float* rays_o  = (const float*)d_in[0];
    const float* rays_d  = (const float*)d_in[1];
    const float* bg      = (const float*)d_in[2];
    const float* p01     = (const float*)d_in[3];
    const float* p02     = (const float*)d_in[4];
    const float* p12     = (const float*)d_in[5];
    const float* feats   = (const float*)d_in[6];
    const float* w1      = (const float*)d_in[7];
    const float* b1      = (const float*)d_in[8];
    const float* w2      = (const float*)d_in[9];
    const float* b2      = (const float*)d_in[10];
    const float* wc1     = (const float*)d_in[11];
    const float* bc1     = (const float*)d_in[12];
    const float* wc2     = (const float*)d_in[13];
    const float* bc2     = (const float*)d_in[14];
    const float* aabb    = (const float*)d_in[15];
    float* out = (float*)d_out;

    nerf_fused<<<NRAYS, 128, 0, stream>>>(rays_o, rays_d, bg, p01, p02, p12, feats,
                                          w1, b1, w2, b2, wc1, bc1, wc2, bc2, aabb, out);
}

// Round 4
// 145.472 us; speedup vs baseline: 78.4774x; 15.2643x over previous
//
#include <hip/hip_runtime.h>

#define NS 128
#define NRAYS 8192

typedef unsigned short u16;
typedef unsigned short u16x8 __attribute__((ext_vector_type(8)));
typedef __bf16 b16x8 __attribute__((ext_vector_type(8)));
typedef float f32x4 __attribute__((ext_vector_type(4)));

__device__ __forceinline__ float clampf(float x, float lo, float hi) {
    return fminf(fmaxf(x, lo), hi);
}

// f32 -> bf16 bits, round-to-nearest-even
__device__ __forceinline__ u16 f2bf(float f) {
    union { float f; unsigned u; } v; v.f = f;
    unsigned u = v.u;
    return (u16)((u + 0x7FFFu + ((u >> 16) & 1u)) >> 16);
}

__device__ __forceinline__ f32x4 mfma_bf16(u16x8 a, u16x8 b, f32x4 c) {
    return __builtin_amdgcn_mfma_f32_16x16x32_bf16(
        __builtin_bit_cast(b16x8, a), __builtin_bit_cast(b16x8, b), c, 0, 0, 0);
}

// swizzled index (u16 units) into a [16][64] bf16 tile, 128B rows.
// XOR row bits into byte bits 4-6 -> u16-index bits 3-5. Bijective per row;
// keeps 8-element blocks intact (reads are 8-aligned).
#define SWZ(r, c) ((((r) * 64) + (c)) ^ (((r) & 7) << 3))

__device__ __forceinline__ void plane_interp(const float* __restrict__ g,
                                             float ca, float cb, float o[3]) {
    float pa = clampf((ca + 1.f) * (0.5f * 127.f), 0.f, 127.f);
    float pb = clampf((cb + 1.f) * (0.5f * 127.f), 0.f, 127.f);
    int la = (int)pa; if (la > 126) la = 126;
    int lb = (int)pb; if (lb > 126) lb = 126;
    float fa = pa - (float)la, fb = pb - (float)lb;
    float w00 = (1.f - fa) * (1.f - fb);
    float w01 = (1.f - fa) * fb;
    float w10 = fa * (1.f - fb);
    float w11 = fa * fb;
    const float* p = g + la * 128 + lb;
#pragma unroll
    for (int c = 0; c < 3; ++c) {
        const float* q = p + c * 16384;
        o[c] = q[0] * w00 + q[1] * w01 + q[128] * w10 + q[129] * w11;
    }
}

__global__ __launch_bounds__(256)
void nerf_mfma(const float* __restrict__ rays_o,
               const float* __restrict__ rays_d,
               const float* __restrict__ bg_color,
               const float* __restrict__ plane01,
               const float* __restrict__ plane02,
               const float* __restrict__ plane12,
               const float* __restrict__ features,
               const float* __restrict__ w1, const float* __restrict__ b1,
               const float* __restrict__ w2, const float* __restrict__ b2,
               const float* __restrict__ wc1, const float* __restrict__ bc1,
               const float* __restrict__ wc2, const float* __restrict__ bc2,
               const float* __restrict__ aabb,
               float* __restrict__ out)
{
    // per-wave private LDS (no cross-wave sharing -> no __syncthreads needed)
    __shared__ __align__(16) u16  s_trans[4][16 * 64];  // h / h2 transpose tile
    __shared__ __align__(16) u16  s_cin[4][16 * 64];    // color-MLP A tile
    __shared__ float s_tau[4][128];
    __shared__ float s_rgb[4][3][128];

    const int tid  = threadIdx.x;
    const int wv   = tid >> 6;
    const int lane = tid & 63;
    const int c16  = lane & 15;   // MFMA row/col selector
    const int kg   = lane >> 4;   // k-group (8 elems each)
    const int ray  = blockIdx.x * 4 + wv;

    // ---- weight B-fragments (held in VGPRs for the whole kernel) ----
    // B layout for 16x16x32: lane holds col = lane&15, k = (lane>>4)*8 + j
    u16x8 Bw1[4], Bwc1[4], Bw2[2], Bwc2[2];
#pragma unroll
    for (int nb = 0; nb < 4; ++nb) {
#pragma unroll
        for (int j = 0; j < 8; ++j) {
            int k = kg * 8 + j;
            Bw1[nb][j]  = f2bf(w1[k * 64 + nb * 16 + c16]);
            Bwc1[nb][j] = f2bf(k < 18 ? wc1[k * 64 + nb * 16 + c16] : 0.f);
        }
    }
#pragma unroll
    for (int ks = 0; ks < 2; ++ks) {
#pragma unroll
        for (int j = 0; j < 8; ++j) {
            int k = ks * 32 + kg * 8 + j;
            Bw2[ks][j]  = f2bf(w2[k * 16 + c16]);
            Bwc2[ks][j] = f2bf(c16 < 3 ? wc2[k * 3 + c16] : 0.f);
        }
    }
    float b1v[4], bc1v[4];
#pragma unroll
    for (int nb = 0; nb < 4; ++nb) {
        b1v[nb]  = b1[nb * 16 + c16];
        bc1v[nb] = bc1[nb * 16 + c16];
    }
    float b2v  = b2[c16];
    float bc2v = (c16 < 3) ? bc2[c16] : 0.f;

    // ---- per-ray setup ----
    float ox = rays_o[ray * 3 + 0], oy = rays_o[ray * 3 + 1], oz = rays_o[ray * 3 + 2];
    float dx = rays_d[ray * 3 + 0], dy = rays_d[ray * 3 + 1], dz = rays_d[ray * 3 + 2];
    float rn = rsqrtf(dx * dx + dy * dy + dz * dz);
    dx *= rn; dy *= rn; dz *= rn;

    float lo0 = aabb[0], lo1 = aabb[1], lo2 = aabb[2];
    float hi0 = aabb[3], hi1 = aabb[4], hi2 = aabb[5];

    float invx = 1.f / dx, invy = 1.f / dy, invz = 1.f / dz;
    float tx0 = (lo0 - ox) * invx, tx1 = (hi0 - ox) * invx;
    float ty0 = (lo1 - oy) * invy, ty1 = (hi1 - oy) * invy;
    float tz0 = (lo2 - oz) * invz, tz1 = (hi2 - oz) * invz;
    float tnear = fmaxf(fmaxf(fminf(tx0, tx1), fminf(ty0, ty1)), fminf(tz0, tz1));
    tnear = fmaxf(tnear, 0.f);
    float tfar = fminf(fminf(fmaxf(tx0, tx1), fmaxf(ty0, ty1)), fmaxf(tz0, tz1));
    tfar = fmaxf(tfar, tnear);
    float delta = (tfar - tnear) * (1.f / (float)NS);

    // ---- init cin tile: zero all (pads k=18..31), then dir in cols 0..2 ----
    for (int i = lane; i < 16 * 64; i += 64) s_cin[wv][i] = 0;
    if (lane < 16) {
        s_cin[wv][SWZ(lane, 0)] = f2bf(dx);
        s_cin[wv][SWZ(lane, 1)] = f2bf(dy);
        s_cin[wv][SWZ(lane, 2)] = f2bf(dz);
    }

    // ---- 8 chunks of 16 samples ----
    for (int c = 0; c < 8; ++c) {
        // this lane gathers features for sample row c16, channels kg*8..kg*8+7
        int s = c * 16 + c16;
        float t = tnear + delta * ((float)s + 0.5f);
        float px = ox + dx * t, py = oy + dy * t, pz = oz + dz * t;
        px = (px - lo0) * (2.f / (hi0 - lo0)) - 1.f;
        py = (py - lo1) * (2.f / (hi1 - lo1)) - 1.f;
        pz = (pz - lo2) * (2.f / (hi2 - lo2)) - 1.f;

        float p01[3], p02[3], p12[3];
        plane_interp(plane01, px, py, p01);
        plane_interp(plane02, px, pz, p02);
        plane_interp(plane12, py, pz, p12);
        float gx = p01[0] * p02[0] * p12[0];
        float gy = p01[1] * p02[1] * p12[1];
        float gz = p01[2] * p02[2] * p12[2];

        float qx = clampf((gx + 1.f) * (0.5f * 63.f), 0.f, 63.f);
        float qy = clampf((gy + 1.f) * (0.5f * 63.f), 0.f, 63.f);
        float qz = clampf((gz + 1.f) * (0.5f * 63.f), 0.f, 63.f);
        int ixg = (int)qx; if (ixg > 62) ixg = 62;
        int iyg = (int)qy; if (iyg > 62) iyg = 62;
        int izg = (int)qz; if (izg > 62) izg = 62;
        float fx = qx - (float)ixg, fy = qy - (float)iyg, fz = qz - (float)izg;
        float wx0 = 1.f - fx, wy0 = 1.f - fy, wz0 = 1.f - fz;
        float cw0 = wx0 * wy0 * wz0, cw1 = wx0 * wy0 * fz;
        float cw2 = wx0 * fy  * wz0, cw3 = wx0 * fy  * fz;
        float cw4 = fx  * wy0 * wz0, cw5 = fx  * wy0 * fz;
        float cw6 = fx  * fy  * wz0, cw7 = fx  * fy  * fz;
        const float* fbase = features + (ixg * 4096 + iyg * 64 + izg);

        // A1 fragment: 8 gathered+interp'd channels, bf16
        u16x8 a1;
#pragma unroll
        for (int j = 0; j < 8; ++j) {
            const float* f = fbase + (size_t)(kg * 8 + j) * 262144;
            float v = cw0 * f[0]    + cw1 * f[1]
                    + cw2 * f[64]   + cw3 * f[65]
                    + cw4 * f[4096] + cw5 * f[4097]
                    + cw6 * f[4160] + cw7 * f[4161];
            a1[j] = f2bf(v);
        }

        // GEMM1: h[16x64] = A1 @ w1 + b1
        f32x4 acc[4];
#pragma unroll
        for (int nb = 0; nb < 4; ++nb) {
            f32x4 ci; ci[0] = ci[1] = ci[2] = ci[3] = b1v[nb];
            acc[nb] = mfma_bf16(a1, Bw1[nb], ci);
        }
        // relu -> bf16 -> transpose tile (C layout: col=c16, rows kg*4+q)
#pragma unroll
        for (int nb = 0; nb < 4; ++nb)
#pragma unroll
            for (int q = 0; q < 4; ++q) {
                int r = kg * 4 + q;
                s_trans[wv][SWZ(r, nb * 16 + c16)] = f2bf(fmaxf(acc[nb][q], 0.f));
            }
        asm volatile("s_waitcnt lgkmcnt(0)" ::: "memory");

        // GEMM2: so[16x16] = relu(h) @ w2 + b2   (K=64 -> 2 steps)
        f32x4 acc2; acc2[0] = acc2[1] = acc2[2] = acc2[3] = b2v;
#pragma unroll
        for (int ks = 0; ks < 2; ++ks) {
            u16x8 a2 = *(const u16x8*)&s_trans[wv][SWZ(c16, ks * 32 + kg * 8)];
            acc2 = mfma_bf16(a2, Bw2[ks], acc2);
        }

        // density (col 0) -> tau ; so[1:16] -> cin cols 3..17
        if (c16 == 0) {
#pragma unroll
            for (int q = 0; q < 4; ++q) {
                float d = __expf(clampf(acc2[q], -15.f, 15.f));
                s_tau[wv][c * 16 + kg * 4 + q] = d * delta;
            }
        } else {
#pragma unroll
            for (int q = 0; q < 4; ++q) {
                int r = kg * 4 + q;
                s_cin[wv][SWZ(r, c16 + 2)] = f2bf(acc2[q]);
            }
        }
        asm volatile("s_waitcnt lgkmcnt(0)" ::: "memory");

        // GEMM3: h2[16x64] = cin @ wc1 + bc1  (K=32, rows>=18 zero in B)
        u16x8 a3 = *(const u16x8*)&s_cin[wv][SWZ(c16, kg * 8)];
        f32x4 acc3[4];
#pragma unroll
        for (int nb = 0; nb < 4; ++nb) {
            f32x4 ci; ci[0] = ci[1] = ci[2] = ci[3] = bc1v[nb];
            acc3[nb] = mfma_bf16(a3, Bwc1[nb], ci);
        }
#pragma unroll
        for (int nb = 0; nb < 4; ++nb)
#pragma unroll
            for (int q = 0; q < 4; ++q) {
                int r = kg * 4 + q;
                s_trans[wv][SWZ(r, nb * 16 + c16)] = f2bf(fmaxf(acc3[nb][q], 0.f));
            }
        asm volatile("s_waitcnt lgkmcnt(0)" ::: "memory");

        // GEMM4: rgb[16x3] = relu(h2) @ wc2 + bc2 (N padded to 16)
        f32x4 acc4; acc4[0] = acc4[1] = acc4[2] = acc4[3] = bc2v;
#pragma unroll
        for (int ks = 0; ks < 2; ++ks) {
            u16x8 a4 = *(const u16x8*)&s_trans[wv][SWZ(c16, ks * 32 + kg * 8)];
            acc4 = mfma_bf16(a4, Bwc2[ks], acc4);
        }
        if (c16 < 3) {
#pragma unroll
            for (int q = 0; q < 4; ++q) {
                float sg = 1.f / (1.f + __expf(-acc4[q]));
                s_rgb[wv][c16][c * 16 + kg * 4 + q] = sg;
            }
        }
    }
    asm volatile("s_waitcnt lgkmcnt(0)" ::: "memory");

    // ---- per-ray exponential integration (2 samples per lane) ----
    float t0 = s_tau[wv][lane];
    float t1 = s_tau[wv][64 + lane];
    float x0 = t0, x1 = t1;
#pragma unroll
    for (int off = 1; off < 64; off <<= 1) {
        float y = __shfl_up(x0, off);
        if (lane >= off) x0 += y;
    }
    float tot0 = __shfl(x0, 63);
#pragma unroll
    for (int off = 1; off < 64; off <<= 1) {
        float y = __shfl_up(x1, off);
        if (lane >= off) x1 += y;
    }
    x1 += tot0;

    float w0 = __expf(t0 - x0) * (1.f - __expf(-t0));
    float w1s = __expf(t1 - x1) * (1.f - __expf(-t1));

    float v0 = w0 * s_rgb[wv][0][lane] + w1s * s_rgb[wv][0][64 + lane];
    float v1 = w0 * s_rgb[wv][1][lane] + w1s * s_rgb[wv][1][64 + lane];
    float v2 = w0 * s_rgb[wv][2][lane] + w1s * s_rgb[wv][2][64 + lane];
    float v3 = w0 + w1s;
#pragma unroll
    for (int off = 32; off; off >>= 1) {
        v0 += __shfl_xor(v0, off);
        v1 += __shfl_xor(v1, off);
        v2 += __shfl_xor(v2, off);
        v3 += __shfl_xor(v3, off);
    }
    if (lane == 0) {
        float bg = bg_color[0];
        out[ray * 3 + 0] = v0 + (1.f - v3) * bg;
        out[ray * 3 + 1] = v1 + (1.f - v3) * bg;
        out[ray * 3 + 2] = v2 + (1.f - v3) * bg;
    }
}

extern "C" void kernel_launch(void* const* d_in, const int* in_sizes, int n_in,
                              void* d_out, int out_size, void* d_ws, size_t ws_size,
                              hipStream_t stream) {
    const float* rays_o  = (const float*)d_in[0];
    const float* rays_d  = (const float*)d_in[1];
    const float* bg      = (const float*)d_in[2];
    const float* p01     = (const float*)d_in[3];
    const float* p02     = (const float*)d_in[4];
    const float* p12     = (const float*)d_in[5];
    const float* feats   = (const float*)d_in[6];
    const float* w1      = (const float*)d_in[7];
    const float* b1      = (const float*)d_in[8];
    const float* w2      = (const float*)d_in[9];
    const float* b2      = (const float*)d_in[10];
    const float* wc1     = (const float*)d_in[11];
    const float* bc1     = (const float*)d_in[12];
    const float* wc2     = (const float*)d_in[13];
    const float* bc2     = (const float*)d_in[14];
    const float* aabb    = (const float*)d_in[15];
    float* out = (float*)d_out;

    nerf_mfma<<<NRAYS / 4, 256, 0, stream>>>(rays_o, rays_d, bg, p01, p02, p12, feats,
                                             w1, b1, w2, b2, wc1, bc1, wc2, bc2, aabb, out);
}

// Round 5
// 116.481 us; speedup vs baseline: 98.0092x; 1.2489x over previous
//
#include <hip/hip_runtime.h>

#define NS 128
#define NRAYS 8192

typedef unsigned short u16;
typedef unsigned int   u32;
typedef unsigned short u16x8 __attribute__((ext_vector_type(8)));
typedef __bf16 b16x8 __attribute__((ext_vector_type(8)));
typedef float f32x4 __attribute__((ext_vector_type(4)));
typedef _Float16 h16x2 __attribute__((ext_vector_type(2)));
typedef unsigned int u32x4 __attribute__((ext_vector_type(4)));

__device__ __forceinline__ float clampf(float x, float lo, float hi) {
    return fminf(fmaxf(x, lo), hi);
}

// f32 -> bf16 bits via native cast (single v_cvt, RNE)
__device__ __forceinline__ u16 f2bf(float f) {
    return __builtin_bit_cast(u16, (__bf16)f);
}

// pack two f32 -> f16x2 dword
__device__ __forceinline__ u32 pkh(float a, float b) {
    h16x2 v; v[0] = (_Float16)a; v[1] = (_Float16)b;
    return __builtin_bit_cast(u32, v);
}
__device__ __forceinline__ float2 uph(u32 u) {
    h16x2 v = __builtin_bit_cast(h16x2, u);
    return make_float2((float)v[0], (float)v[1]);
}

__device__ __forceinline__ f32x4 mfma_bf16(u16x8 a, u16x8 b, f32x4 c) {
    return __builtin_amdgcn_mfma_f32_16x16x32_bf16(
        __builtin_bit_cast(b16x8, a), __builtin_bit_cast(b16x8, b), c, 0, 0, 0);
}

// swizzled index (u16 units) into a [16][64] bf16 tile, 128B rows.
#define SWZ(r, c) ((((r) * 64) + (c)) ^ (((r) & 7) << 3))

__device__ __forceinline__ void plane_interp(const float* __restrict__ g,
                                             float ca, float cb, float o[3]) {
    float pa = clampf((ca + 1.f) * (0.5f * 127.f), 0.f, 127.f);
    float pb = clampf((cb + 1.f) * (0.5f * 127.f), 0.f, 127.f);
    int la = (int)pa; if (la > 126) la = 126;
    int lb = (int)pb; if (lb > 126) lb = 126;
    float fa = pa - (float)la, fb = pb - (float)lb;
    float w00 = (1.f - fa) * (1.f - fb);
    float w01 = (1.f - fa) * fb;
    float w10 = fa * (1.f - fb);
    float w11 = fa * fb;
    const float* p = g + la * 128 + lb;
#pragma unroll
    for (int c = 0; c < 3; ++c) {
        const float* q = p + c * 16384;
        o[c] = q[0] * w00 + q[1] * w01 + q[128] * w10 + q[129] * w11;
    }
}

__global__ __launch_bounds__(256)
void nerf_mfma(const float* __restrict__ rays_o,
               const float* __restrict__ rays_d,
               const float* __restrict__ bg_color,
               const float* __restrict__ plane01,
               const float* __restrict__ plane02,
               const float* __restrict__ plane12,
               const float* __restrict__ features,
               const float* __restrict__ w1, const float* __restrict__ b1,
               const float* __restrict__ w2, const float* __restrict__ b2,
               const float* __restrict__ wc1, const float* __restrict__ bc1,
               const float* __restrict__ wc2, const float* __restrict__ bc2,
               const float* __restrict__ aabb,
               float* __restrict__ out)
{
    // per-wave private LDS (no cross-wave sharing; same-wave DS ops are in-order)
    __shared__ __align__(16) u32  s_interp[4][128][8];  // {4x f16x2 cw, fbase, pad}
    __shared__ __align__(16) u16  s_trans[4][16 * 64];  // h / h2 transpose tile
    __shared__ __align__(16) u16  s_cin[4][16 * 64];    // color-MLP A tile
    __shared__ float s_tau[4][128];
    __shared__ float s_rgb[4][3][128];

    const int tid  = threadIdx.x;
    const int wv   = tid >> 6;
    const int lane = tid & 63;
    const int c16  = lane & 15;   // MFMA row/col selector
    const int kg   = lane >> 4;   // k-group (8 elems each)
    const int ray  = blockIdx.x * 4 + wv;

    // ---- weight B-fragments (VGPR-resident for the whole kernel) ----
    u16x8 Bw1[4], Bwc1[4], Bw2[2], Bwc2[2];
#pragma unroll
    for (int nb = 0; nb < 4; ++nb) {
#pragma unroll
        for (int j = 0; j < 8; ++j) {
            int k = kg * 8 + j;
            Bw1[nb][j]  = f2bf(w1[k * 64 + nb * 16 + c16]);
            Bwc1[nb][j] = f2bf(k < 18 ? wc1[k * 64 + nb * 16 + c16] : 0.f);
        }
    }
#pragma unroll
    for (int ks = 0; ks < 2; ++ks) {
#pragma unroll
        for (int j = 0; j < 8; ++j) {
            int k = ks * 32 + kg * 8 + j;
            Bw2[ks][j]  = f2bf(w2[k * 16 + c16]);
            Bwc2[ks][j] = f2bf(c16 < 3 ? wc2[k * 3 + c16] : 0.f);
        }
    }
    float b1v[4], bc1v[4];
#pragma unroll
    for (int nb = 0; nb < 4; ++nb) {
        b1v[nb]  = b1[nb * 16 + c16];
        bc1v[nb] = bc1[nb * 16 + c16];
    }
    float b2v  = b2[c16];
    float bc2v = (c16 < 3) ? bc2[c16] : 0.f;

    // ---- per-ray setup ----
    float ox = rays_o[ray * 3 + 0], oy = rays_o[ray * 3 + 1], oz = rays_o[ray * 3 + 2];
    float dx = rays_d[ray * 3 + 0], dy = rays_d[ray * 3 + 1], dz = rays_d[ray * 3 + 2];
    float rn = rsqrtf(dx * dx + dy * dy + dz * dz);
    dx *= rn; dy *= rn; dz *= rn;

    float lo0 = aabb[0], lo1 = aabb[1], lo2 = aabb[2];
    float hi0 = aabb[3], hi1 = aabb[4], hi2 = aabb[5];

    float invx = 1.f / dx, invy = 1.f / dy, invz = 1.f / dz;
    float tx0 = (lo0 - ox) * invx, tx1 = (hi0 - ox) * invx;
    float ty0 = (lo1 - oy) * invy, ty1 = (hi1 - oy) * invy;
    float tz0 = (lo2 - oz) * invz, tz1 = (hi2 - oz) * invz;
    float tnear = fmaxf(fmaxf(fminf(tx0, tx1), fminf(ty0, ty1)), fminf(tz0, tz1));
    tnear = fmaxf(tnear, 0.f);
    float tfar = fminf(fminf(fmaxf(tx0, tx1), fmaxf(ty0, ty1)), fmaxf(tz0, tz1));
    tfar = fmaxf(tfar, tnear);
    float delta = (tfar - tnear) * (1.f / (float)NS);

    // ---- coordinate phase: 2 samples/lane, once ----
#pragma unroll
    for (int i = 0; i < 2; ++i) {
        int s = i * 64 + lane;
        float t = tnear + delta * ((float)s + 0.5f);
        float px = ox + dx * t, py = oy + dy * t, pz = oz + dz * t;
        px = (px - lo0) * (2.f / (hi0 - lo0)) - 1.f;
        py = (py - lo1) * (2.f / (hi1 - lo1)) - 1.f;
        pz = (pz - lo2) * (2.f / (hi2 - lo2)) - 1.f;

        float p01[3], p02[3], p12[3];
        plane_interp(plane01, px, py, p01);
        plane_interp(plane02, px, pz, p02);
        plane_interp(plane12, py, pz, p12);
        float gx = p01[0] * p02[0] * p12[0];
        float gy = p01[1] * p02[1] * p12[1];
        float gz = p01[2] * p02[2] * p12[2];

        float qx = clampf((gx + 1.f) * (0.5f * 63.f), 0.f, 63.f);
        float qy = clampf((gy + 1.f) * (0.5f * 63.f), 0.f, 63.f);
        float qz = clampf((gz + 1.f) * (0.5f * 63.f), 0.f, 63.f);
        int ixg = (int)qx; if (ixg > 62) ixg = 62;
        int iyg = (int)qy; if (iyg > 62) iyg = 62;
        int izg = (int)qz; if (izg > 62) izg = 62;
        float fx = qx - (float)ixg, fy = qy - (float)iyg, fz = qz - (float)izg;
        float wx0 = 1.f - fx, wy0 = 1.f - fy, wz0 = 1.f - fz;
        u32* row = s_interp[wv][s];
        row[0] = pkh(wx0 * wy0 * wz0, wx0 * wy0 * fz);
        row[1] = pkh(wx0 * fy  * wz0, wx0 * fy  * fz);
        row[2] = pkh(fx  * wy0 * wz0, fx  * wy0 * fz);
        row[3] = pkh(fx  * fy  * wz0, fx  * fy  * fz);
        row[4] = (u32)(ixg * 4096 + iyg * 64 + izg);
    }

    // ---- init cin tile: zero (pads k=18..31), then dir in cols 0..2 ----
    {
        u32x4 z4 = {0, 0, 0, 0};
        u32x4* zp = (u32x4*)s_cin[wv];
#pragma unroll
        for (int i = lane; i < 128; i += 64) zp[i] = z4;
        if (lane < 16) {
            s_cin[wv][SWZ(lane, 0)] = f2bf(dx);
            s_cin[wv][SWZ(lane, 1)] = f2bf(dy);
            s_cin[wv][SWZ(lane, 2)] = f2bf(dz);
        }
    }

    // ---- 8 chunks of 16 samples ----
    for (int c = 0; c < 8; ++c) {
        // this lane handles sample row c16, channels kg*8..kg*8+7
        const u32* row = s_interp[wv][c * 16 + c16];
        u32x4 cwp = *(const u32x4*)row;
        u32 fb = row[4];
        float2 w01p = uph(cwp[0]);
        float2 w23p = uph(cwp[1]);
        float2 w45p = uph(cwp[2]);
        float2 w67p = uph(cwp[3]);
        const float* fbase = features + fb;

        u16x8 a1;
#pragma unroll
        for (int j = 0; j < 8; ++j) {
            const float* f = fbase + (size_t)(kg * 8 + j) * 262144;
            float v = w01p.x * f[0]    + w01p.y * f[1]
                    + w23p.x * f[64]   + w23p.y * f[65]
                    + w45p.x * f[4096] + w45p.y * f[4097]
                    + w67p.x * f[4160] + w67p.y * f[4161];
            a1[j] = f2bf(v);
        }

        // GEMM1: h[16x64] = A1 @ w1 + b1
        f32x4 acc[4];
#pragma unroll
        for (int nb = 0; nb < 4; ++nb) {
            f32x4 ci; ci[0] = ci[1] = ci[2] = ci[3] = b1v[nb];
            acc[nb] = mfma_bf16(a1, Bw1[nb], ci);
        }
        // relu -> bf16 -> transpose tile (C layout: col=c16, rows kg*4+q)
#pragma unroll
        for (int nb = 0; nb < 4; ++nb)
#pragma unroll
            for (int q = 0; q < 4; ++q) {
                int r = kg * 4 + q;
                s_trans[wv][SWZ(r, nb * 16 + c16)] = f2bf(fmaxf(acc[nb][q], 0.f));
            }

        // GEMM2: so[16x16] = relu(h) @ w2 + b2   (K=64 -> 2 steps)
        f32x4 acc2; acc2[0] = acc2[1] = acc2[2] = acc2[3] = b2v;
#pragma unroll
        for (int ks = 0; ks < 2; ++ks) {
            u16x8 a2 = *(const u16x8*)&s_trans[wv][SWZ(c16, ks * 32 + kg * 8)];
            acc2 = mfma_bf16(a2, Bw2[ks], acc2);
        }

        // density (col 0) -> tau ; so[1:16] -> cin cols 3..17
        if (c16 == 0) {
#pragma unroll
            for (int q = 0; q < 4; ++q) {
                float d = __expf(clampf(acc2[q], -15.f, 15.f));
                s_tau[wv][c * 16 + kg * 4 + q] = d * delta;
            }
        } else {
#pragma unroll
            for (int q = 0; q < 4; ++q) {
                int r = kg * 4 + q;
                s_cin[wv][SWZ(r, c16 + 2)] = f2bf(acc2[q]);
            }
        }

        // GEMM3: h2[16x64] = cin @ wc1 + bc1  (K=32, rows>=18 zero in B)
        u16x8 a3 = *(const u16x8*)&s_cin[wv][SWZ(c16, kg * 8)];
        f32x4 acc3[4];
#pragma unroll
        for (int nb = 0; nb < 4; ++nb) {
            f32x4 ci; ci[0] = ci[1] = ci[2] = ci[3] = bc1v[nb];
            acc3[nb] = mfma_bf16(a3, Bwc1[nb], ci);
        }
#pragma unroll
        for (int nb = 0; nb < 4; ++nb)
#pragma unroll
            for (int q = 0; q < 4; ++q) {
                int r = kg * 4 + q;
                s_trans[wv][SWZ(r, nb * 16 + c16)] = f2bf(fmaxf(acc3[nb][q], 0.f));
            }

        // GEMM4: rgb[16x3] = relu(h2) @ wc2 + bc2 (N padded to 16)
        f32x4 acc4; acc4[0] = acc4[1] = acc4[2] = acc4[3] = bc2v;
#pragma unroll
        for (int ks = 0; ks < 2; ++ks) {
            u16x8 a4 = *(const u16x8*)&s_trans[wv][SWZ(c16, ks * 32 + kg * 8)];
            acc4 = mfma_bf16(a4, Bwc2[ks], acc4);
        }
        if (c16 < 3) {
#pragma unroll
            for (int q = 0; q < 4; ++q) {
                float sg = 1.f / (1.f + __expf(-acc4[q]));
                s_rgb[wv][c16][c * 16 + kg * 4 + q] = sg;
            }
        }
    }

    // ---- per-ray exponential integration (2 samples per lane) ----
    float t0 = s_tau[wv][lane];
    float t1 = s_tau[wv][64 + lane];
    float x0 = t0, x1 = t1;
#pragma unroll
    for (int off = 1; off < 64; off <<= 1) {
        float y = __shfl_up(x0, off);
        if (lane >= off) x0 += y;
    }
    float tot0 = __shfl(x0, 63);
#pragma unroll
    for (int off = 1; off < 64; off <<= 1) {
        float y = __shfl_up(x1, off);
        if (lane >= off) x1 += y;
    }
    x1 += tot0;

    float w0 = __expf(t0 - x0) * (1.f - __expf(-t0));
    float w1s = __expf(t1 - x1) * (1.f - __expf(-t1));

    float v0 = w0 * s_rgb[wv][0][lane] + w1s * s_rgb[wv][0][64 + lane];
    float v1 = w0 * s_rgb[wv][1][lane] + w1s * s_rgb[wv][1][64 + lane];
    float v2 = w0 * s_rgb[wv][2][lane] + w1s * s_rgb[wv][2][64 + lane];
    float v3 = w0 + w1s;
#pragma unroll
    for (int off = 32; off; off >>= 1) {
        v0 += __shfl_xor(v0, off);
        v1 += __shfl_xor(v1, off);
        v2 += __shfl_xor(v2, off);
        v3 += __shfl_xor(v3, off);
    }
    if (lane == 0) {
        float bg = bg_color[0];
        out[ray * 3 + 0] = v0 + (1.f - v3) * bg;
        out[ray * 3 + 1] = v1 + (1.f - v3) * bg;
        out[ray * 3 + 2] = v2 + (1.f - v3) * bg;
    }
}

extern "C" void kernel_launch(void* const* d_in, const int* in_sizes, int n_in,
                              void* d_out, int out_size, void* d_ws, size_t ws_size,
                              hipStream_t stream) {
    const float* rays_o  = (const float*)d_in[0];
    const float* rays_d  = (const float*)d_in[1];
    const float* bg      = (const float*)d_in[2];
    const float* p01     = (const float*)d_in[3];
    const float* p02     = (const float*)d_in[4];
    const float* p12     = (const float*)d_in[5];
    const float* feats   = (const float*)d_in[6];
    const float* w1      = (const float*)d_in[7];
    const float* b1      = (const float*)d_in[8];
    const float* w2      = (const float*)d_in[9];
    const float* b2      = (const float*)d_in[10];
    const float* wc1     = (const float*)d_in[11];
    const float* bc1     = (const float*)d_in[12];
    const float* wc2     = (const float*)d_in[13];
    const float* bc2     = (const float*)d_in[14];
    const float* aabb    = (const float*)d_in[15];
    float* out = (float*)d_out;

    nerf_mfma<<<NRAYS / 4, 256, 0, stream>>>(rays_o, rays_d, bg, p01, p02, p12, feats,
                                             w1, b1, w2, b2, wc1, bc1, wc2, bc2, aabb, out);
}